// Round 8
// baseline (677.550 us; speedup 1.0000x reference)
//
#include <hip/hip_runtime.h>
#include <hip/hip_bf16.h>

typedef __hip_bfloat16 bf16;
typedef __attribute__((ext_vector_type(8))) short bf16x8s;
typedef __attribute__((ext_vector_type(4))) float f32x4;
typedef __attribute__((ext_vector_type(4))) int i32x4;

#define NB 64
#define NS 32
#define NV 10000
#define NE 512
#define NH 512
#define NF 2048
#define ND 1024
#define PRE_SLOTS 8

static __device__ __forceinline__ float bf2f(bf16 x) { return __bfloat162float(x); }
static __device__ __forceinline__ bf16 f2bf(float x) { return __float2bfloat16(x); }
static __device__ __forceinline__ f32x4 mfma16(bf16x8s a, bf16x8s b, f32x4 c) {
  return __builtin_amdgcn_mfma_f32_16x16x32_bf16(a, b, c, 0, 0, 0);
}

// ---- LLC-coherent (cross-XCD) accesses, bypass per-XCD L1/L2 via sc0 sc1.
// Compiler does NOT track vmcnt for these — explicit s_waitcnt before use.
static __device__ __forceinline__ i32x4 ld16_sc(const void* p) {
  i32x4 r;
  asm volatile("global_load_dwordx4 %0, %1, off sc0 sc1" : "=v"(r) : "v"(p) : "memory");
  return r;
}
static __device__ __forceinline__ float lddw_sc(const void* p) {
  float r;
  asm volatile("global_load_dword %0, %1, off sc0 sc1" : "=v"(r) : "v"(p) : "memory");
  return r;
}
static __device__ __forceinline__ void stus_sc(void* p, unsigned v) {
  asm volatile("global_store_short %0, %1, off sc0 sc1" :: "v"(p), "v"(v) : "memory");
}
static __device__ __forceinline__ void stud_sc(void* p, unsigned v) {
  asm volatile("global_store_dword %0, %1, off sc0 sc1" :: "v"(p), "v"(v) : "memory");
}

// One 16x16 output tile per wave (cached path, for the plain GEMMs).
__device__ __forceinline__ f32x4 wave_tile16(const bf16* A, const bf16* BT,
                                             int lda, int K, int m0, int n0) {
  int lane = threadIdx.x & 63;
  int r = lane & 15, g = lane >> 4;
  const bf16* ap = A + (size_t)(m0 + r) * lda + g * 8;
  const bf16* bp = BT + (size_t)(n0 + r) * K + g * 8;
  f32x4 acc = {0.f, 0.f, 0.f, 0.f};
#pragma unroll 4
  for (int k = 0; k < K; k += 32) {
    bf16x8s a = *(const bf16x8s*)(ap + k);
    bf16x8s b = *(const bf16x8s*)(bp + k);
    acc = mfma16(a, b, acc);
  }
  return acc;
}

// ---------------- embedding gather + f32->bf16 ----------------
__global__ void k_embed(const int* __restrict__ tokens, const float* __restrict__ emb,
                        bf16* __restrict__ x0) {
  int row = blockIdx.x;
  int tok = tokens[row];
  const float2* src = (const float2*)(emb + (size_t)tok * NE);
  uint32_t* dst = (uint32_t*)(x0 + (size_t)row * NE);
  float2 v = src[threadIdx.x];
  __hip_bfloat162 p;
  p.x = f2bf(v.x); p.y = f2bf(v.y);
  dst[threadIdx.x] = *(uint32_t*)&p;
}

__global__ void k_cvt(const float* __restrict__ src, bf16* __restrict__ dst, int n) {
  int i = blockIdx.x * 256 + threadIdx.x;
  if (i < n) dst[i] = f2bf(src[i]);
}

__global__ void k_transpose(const float* __restrict__ src, bf16* __restrict__ dst,
                            int K, int N) {
  __shared__ float tile[32][33];
  int n0 = blockIdx.x * 32, k0 = blockIdx.y * 32;
  int tx = threadIdx.x & 31, ty = threadIdx.x >> 5;
  for (int i = ty; i < 32; i += 8) {
    int k = k0 + i, n = n0 + tx;
    tile[i][tx] = (k < K && n < N) ? src[(size_t)k * N + n] : 0.f;
  }
  __syncthreads();
  for (int i = ty; i < 32; i += 8) {
    int n = n0 + i, k = k0 + tx;
    if (n < N && k < K) dst[(size_t)n * K + k] = f2bf(tile[tx][i]);
  }
}

__global__ void k_transpose12(const float* __restrict__ w_r, const float* __restrict__ w_u,
                              const float* __restrict__ w_h, bf16* __restrict__ ruhT,
                              bf16* __restrict__ hhT, bf16* __restrict__ xT) {
  int z = blockIdx.z, l = z / 6, q = z % 6;
  const float* srcs[6] = {
    w_r + (size_t)l * ND * NH + (size_t)512 * NH,
    w_u + (size_t)l * ND * NH + (size_t)512 * NH,
    w_h + (size_t)l * ND * NH + (size_t)512 * NH,
    w_r + (size_t)l * ND * NH,
    w_u + (size_t)l * ND * NH,
    w_h + (size_t)l * ND * NH };
  bf16* dsts[6] = {
    ruhT + (size_t)l * 1024 * 512,
    ruhT + (size_t)l * 1024 * 512 + 512 * 512,
    hhT  + (size_t)l * 512 * 512,
    xT   + (size_t)l * 1536 * 512,
    xT   + (size_t)l * 1536 * 512 + 512 * 512,
    xT   + (size_t)l * 1536 * 512 + 1024 * 512 };
  const float* src = srcs[q];
  bf16* dst = dsts[q];
  __shared__ float tile[32][33];
  int n0 = blockIdx.x * 32, k0 = blockIdx.y * 32;
  int tx = threadIdx.x & 31, ty = threadIdx.x >> 5;
  for (int i = ty; i < 32; i += 8)
    tile[i][tx] = src[(size_t)(k0 + i) * NH + n0 + tx];
  __syncthreads();
  for (int i = ty; i < 32; i += 8)
    dst[(size_t)(n0 + i) * NH + k0 + tx] = f2bf(tile[tx][i]);
}

__global__ void k_bias3all(const float* __restrict__ br, const float* __restrict__ bu,
                           const float* __restrict__ bh, float* __restrict__ bias) {
  int i = blockIdx.x * 256 + threadIdx.x;
  if (i < 3072) {
    int l = i / 1536, c = i % 1536;
    const float* s = (c < 512) ? (br + l * 512 + c)
                   : (c < 1024 ? (bu + l * 512 + (c - 512)) : (bh + l * 512 + (c - 1024)));
    bias[i] = *s;
  }
}

// ---------------- h0 = cnn @ w_in + b_in, dual-store f32 + bf16 ----------------
__global__ void k_gemm_h0(const bf16* __restrict__ A, const bf16* __restrict__ BT,
                          const float* __restrict__ bias,
                          float* __restrict__ h0f, bf16* __restrict__ h0b) {
  int wid = blockIdx.x * 4 + (threadIdx.x >> 6);
  int mt = wid & 3, nt = wid >> 2;
  f32x4 acc = wave_tile16(A, BT, NF, NF, mt * 16, nt * 16);
  int lane = threadIdx.x & 63;
  int cl = lane & 15, g = lane >> 4;
  int col = nt * 16 + cl;
  float bv = bias[col];
#pragma unroll
  for (int j = 0; j < 4; j++) {
    int row = mt * 16 + g * 4 + j;
    float v = acc[j] + bv;
    h0f[(size_t)row * NH + col] = v;
    h0b[(size_t)row * NH + col] = f2bf(v);
  }
}

// ---------------- fused persistent 2-layer GRU + pre-workers ----------------
// 96 WGs x 512 thr, all co-resident (1 WG/CU). WGs 0..63: recurrence (layer=bid>>5,
// group m=bid&3 owns batches m*16..+15, wgc=(bid&31)>>2 owns h-cols wgc*64..+64).
// Redundant-r: every WG holds the FULL W_r (4 tiles/wave, 256 VGPR) and computes the
// whole r-vector locally -> rh panel stays in LDS -> ONE LLC handoff (h) per step.
// WGs 64..95: pre-workers (16/layer) computing pre(t)=x(t)@Wx+b into an 8-slot ring;
// layer1's x(t)=layer0's h(t) (gated on layer0 h-flags). All cross-WG data via
// sc0sc1 (LLC) + monotonic per-WG flag words; no cache maintenance anywhere.
__global__ __launch_bounds__(512, 1)
void k_gru2(const bf16* __restrict__ w_ruh, const bf16* __restrict__ w_hh,
            const bf16* __restrict__ w_x, const float* __restrict__ bias3,
            const float* __restrict__ h0f, const bf16* __restrict__ h0b,
            const bf16* __restrict__ x0, bf16* __restrict__ seq0,
            bf16* __restrict__ seq1, float* __restrict__ pre,
            unsigned* __restrict__ flags) {
  __shared__ char lds[36864];
  const int tid = threadIdx.x;
  const int lane = tid & 63;
  const int wv = tid >> 6;
  const int cl = lane & 15, g = lane >> 4;
  const int bid = blockIdx.x;

  // poll helpers: single-lane LLC poll, then barrier
  auto pollmin8 = [&](const unsigned* f, unsigned tgt) {
    if (tid == 0) {
      for (;;) {
        i32x4 a = ld16_sc(f);
        i32x4 b = ld16_sc(f + 4);
        asm volatile("s_waitcnt vmcnt(0)" ::: "memory");
        unsigned mn = min(min(min((unsigned)a[0], (unsigned)a[1]),
                              min((unsigned)a[2], (unsigned)a[3])),
                          min(min((unsigned)b[0], (unsigned)b[1]),
                              min((unsigned)b[2], (unsigned)b[3])));
        if (mn >= tgt) break;
        __builtin_amdgcn_s_sleep(1);
      }
    }
    __syncthreads();
    __builtin_amdgcn_sched_barrier(0);
  };
  auto pollmin4 = [&](const unsigned* f, unsigned tgt) {
    if (tid == 0) {
      for (;;) {
        i32x4 a = ld16_sc(f);
        asm volatile("s_waitcnt vmcnt(0)" ::: "memory");
        unsigned mn = min(min((unsigned)a[0], (unsigned)a[1]),
                          min((unsigned)a[2], (unsigned)a[3]));
        if (mn >= tgt) break;
        __builtin_amdgcn_s_sleep(1);
      }
    }
    __syncthreads();
    __builtin_amdgcn_sched_barrier(0);
  };
  // stage a 16x512 bf16 slab -> swizzled LDS panel; lane-stride-16B (conflict-free)
  auto stage = [&](char* dst, const char* src, int rstr) {
    int r0 = tid >> 6, in0 = (tid & 63) * 16;   // each wave covers one full row
    i32x4 v0 = ld16_sc(src + (size_t)r0 * rstr + in0);
    i32x4 v1 = ld16_sc(src + (size_t)(r0 + 8) * rstr + in0);
    asm volatile("s_waitcnt vmcnt(0)" ::: "memory");
    __builtin_amdgcn_sched_barrier(0);
    *(i32x4*)(dst + r0 * 1024 + (in0 ^ ((r0 & 7) << 4))) = v0;
    *(i32x4*)(dst + (r0 + 8) * 1024 + (in0 ^ (((r0 + 8) & 7) << 4))) = v1;
  };
  auto afrag = [&](const char* panel, int kk) {
    return *(const bf16x8s*)(panel + cl * 1024 + ((kk * 64 + g * 16) ^ ((cl & 7) << 4)));
  };

  if (bid < 64) {
    // ================= recurrence WG =================
    const int l = bid >> 5, w5 = bid & 31, m = w5 & 3, wgc = w5 >> 2;
    unsigned* fl = flags + (l * 4 + m) * 32;
    const bf16* Wruh = w_ruh + (size_t)l * 1024 * 512;
    bf16* seql = l ? seq1 : seq0;
    float* prel = pre + (size_t)l * PRE_SLOTS * 64 * 1536;
    char* hpan = lds;
    char* rpan = lds + 16384;
    float* ul = (float*)(lds + 32768);

    // full W_r share: wave wv covers r-cols [wv*64, wv*64+64)
    bf16x8s wr[4][16];
#pragma unroll
    for (int i = 0; i < 4; i++) {
      const bf16* p = Wruh + (size_t)(wv * 64 + i * 16 + cl) * 512 + g * 8;
#pragma unroll
      for (int kk = 0; kk < 16; kk++) wr[i][kk] = *(const bf16x8s*)(p + kk * 32);
    }
    // phase-B weights: waves 0-3 = W_u (own 16 cols), waves 4-7 = W_h (own 16 cols)
    bf16x8s wx[16];
    float h_reg[4] = {0.f, 0.f, 0.f, 0.f};
    const int ocol = wgc * 64 + (wv & 3) * 16 + cl;   // own output col
    if (wv < 4) {
      const bf16* p = Wruh + (size_t)(512 + ocol) * 512 + g * 8;
#pragma unroll
      for (int kk = 0; kk < 16; kk++) wx[kk] = *(const bf16x8s*)(p + kk * 32);
    } else {
      const bf16* p = w_hh + (size_t)l * 512 * 512 + (size_t)ocol * 512 + g * 8;
#pragma unroll
      for (int kk = 0; kk < 16; kk++) wx[kk] = *(const bf16x8s*)(p + kk * 32);
#pragma unroll
      for (int j = 0; j < 4; j++)
        h_reg[j] = h0f[(size_t)(m * 16 + g * 4 + j) * 512 + ocol];
    }

#pragma unroll 1
    for (int t = 0; t < NS; t++) {
      if (t) pollmin8(fl, (unsigned)t);              // h(t-1) from all 8 WGs
      pollmin4(fl + 8, (unsigned)(t + 1));           // pre slot t from all 4 workers
      if (t == 0) stage(hpan, (const char*)h0b + (size_t)m * 16 * 1024, 1024);
      else stage(hpan, (const char*)seql + ((size_t)(m * 16) * NS + (t - 1)) * 1024,
                 NS * 1024);
      __syncthreads();
      // issue pre sc-loads (consumed after MFMAs)
      float pr[4][4], px[4];
      const size_t prow = (size_t)(t & 7) * 64 + m * 16;
#pragma unroll
      for (int i = 0; i < 4; i++)
#pragma unroll
        for (int j = 0; j < 4; j++)
          pr[i][j] = lddw_sc(&prel[(prow + g * 4 + j) * 1536 + wv * 64 + i * 16 + cl]);
      {
        const int cB = (wv < 4) ? (512 + ocol) : (1024 + ocol);
#pragma unroll
        for (int j = 0; j < 4; j++)
          px[j] = lddw_sc(&prel[(prow + g * 4 + j) * 1536 + cB]);
      }
      // r-phase: full r for this wave's 64 cols (A shared across 4 col-tiles)
      f32x4 a0 = {0.f,0.f,0.f,0.f}, a1 = a0, a2 = a0, a3 = a0;
#pragma unroll
      for (int kk = 0; kk < 16; kk++) {
        bf16x8s a = afrag(hpan, kk);
        a0 = mfma16(a, wr[0][kk], a0);
        a1 = mfma16(a, wr[1][kk], a1);
        a2 = mfma16(a, wr[2][kk], a2);
        a3 = mfma16(a, wr[3][kk], a3);
      }
      asm volatile("s_waitcnt vmcnt(0)" ::: "memory");   // pre loads done
      __builtin_amdgcn_sched_barrier(0);
      // r gates -> rh panel (LDS only)
#pragma unroll
      for (int i = 0; i < 4; i++) {
        f32x4 acc = (i == 0) ? a0 : (i == 1) ? a1 : (i == 2) ? a2 : a3;
        const int col = wv * 64 + i * 16 + cl;
#pragma unroll
        for (int j = 0; j < 4; j++) {
          const int row = g * 4 + j;
          const int boff = row * 1024 + ((col * 2) ^ ((row & 7) << 4));
          unsigned short hv = *(const unsigned short*)(hpan + boff);
          float gate = 1.f / (1.f + expf(-(acc[j] + pr[i][j])));
          bf16 hb_ = *(bf16*)&hv;
          bf16 rhv = f2bf(gate * bf2f(hb_));
          *(unsigned short*)(rpan + boff) = *(unsigned short*)&rhv;
        }
      }
      // u-gate (waves 0-3), result to LDS
      if (wv < 4) {
        f32x4 au = {0.f,0.f,0.f,0.f};
#pragma unroll
        for (int kk = 0; kk < 16; kk++) au = mfma16(afrag(hpan, kk), wx[kk], au);
#pragma unroll
        for (int j = 0; j < 4; j++)
          ul[wv * 256 + (g * 4 + j) * 16 + cl] = 1.f / (1.f + expf(-(au[j] + px[j])));
      }
      __syncthreads();
      // h_tilde + combine (waves 4-7), sc-store h into seq
      if (wv >= 4) {
        f32x4 ah = {0.f,0.f,0.f,0.f};
#pragma unroll
        for (int kk = 0; kk < 16; kk++) ah = mfma16(afrag(rpan, kk), wx[kk], ah);
#pragma unroll
        for (int j = 0; j < 4; j++) {
          float htil = tanhf(ah[j] + px[j]);
          float u = ul[(wv - 4) * 256 + (g * 4 + j) * 16 + cl];
          float hnew = h_reg[j] * u + (1.f - u) * htil;
          h_reg[j] = hnew;
          bf16 hn = f2bf(hnew);
          int b = m * 16 + g * 4 + j;
          stus_sc((void*)(seql + ((size_t)b * NS + t) * 512 + ocol),
                  *(unsigned short*)&hn);
        }
      }
      asm volatile("s_waitcnt vmcnt(0)" ::: "memory");   // h stores ack'd at LLC
      __syncthreads();
      if (tid == 0) stud_sc(&fl[wgc], (unsigned)(t + 1));
    }
  } else {
    // ================= pre-worker WG =================
    const int wb = bid - 64, wl = wb >> 4, q = wb & 15, wm = q & 3, cw = q >> 2;
    unsigned* flo = flags + (wl * 4 + wm) * 32;
    unsigned* fl0 = flags + wm * 32;
    const bf16* xsrc = wl ? seq0 : x0;
    float* prel = pre + (size_t)wl * PRE_SLOTS * 64 * 1536;
    char* xpan = lds;
    const int ct0 = cw * 24 + wv * 3;                // 3 col-tiles of 96
    bf16x8s wxw[3][16];
#pragma unroll
    for (int i = 0; i < 3; i++) {
      const bf16* p = w_x + (size_t)wl * 1536 * 512 + (size_t)((ct0 + i) * 16 + cl) * 512 + g * 8;
#pragma unroll
      for (int kk = 0; kk < 16; kk++) wxw[i][kk] = *(const bf16x8s*)(p + kk * 32);
    }
    float br[3];
#pragma unroll
    for (int i = 0; i < 3; i++) br[i] = bias3[wl * 1536 + (ct0 + i) * 16 + cl];

#pragma unroll 1
    for (int t = 0; t < NS; t++) {
      if (wl) pollmin8(fl0, (unsigned)(t + 1));      // x(t) = layer0 h(t)
      if (t >= 7) pollmin8(flo, (unsigned)(t - 6));  // ring-overwrite gate
      stage(xpan, (const char*)xsrc + ((size_t)(wm * 16) * NS + t) * 1024, NS * 1024);
      __syncthreads();
      f32x4 c0 = {0.f,0.f,0.f,0.f}, c1 = c0, c2 = c0;
#pragma unroll
      for (int kk = 0; kk < 16; kk++) {
        bf16x8s a = afrag(xpan, kk);
        c0 = mfma16(a, wxw[0][kk], c0);
        c1 = mfma16(a, wxw[1][kk], c1);
        c2 = mfma16(a, wxw[2][kk], c2);
      }
#pragma unroll
      for (int i = 0; i < 3; i++) {
        f32x4 acc = (i == 0) ? c0 : (i == 1) ? c1 : c2;
#pragma unroll
        for (int j = 0; j < 4; j++) {
          union { float f; unsigned u; } cv;
          cv.f = acc[j] + br[i];
          stud_sc(&prel[((size_t)(t & 7) * 64 + wm * 16 + g * 4 + j) * 1536 +
                        (ct0 + i) * 16 + cl], cv.u);
        }
      }
      asm volatile("s_waitcnt vmcnt(0)" ::: "memory");
      __syncthreads();
      if (tid == 0) stud_sc(&flo[8 + cw], (unsigned)(t + 1));
    }
  }
}

// ---------------- logits = seq1 @ w_out + b_out, depth-1 reg prefetch ----------------
__global__ void k_gemm_out(const bf16* __restrict__ A, const bf16* __restrict__ BT,
                           const float* __restrict__ bias, float* __restrict__ out) {
  int wid = blockIdx.x * 4 + (threadIdx.x >> 6);
  int mg = wid % 32, ng = wid / 32;
  int lane = threadIdx.x & 63;
  int cl = lane & 15, g = lane >> 4;
  f32x4 acc[4][4] = {};
  const bf16* a0 = A + (size_t)(mg * 64 + cl) * NE + g * 8;
  const bf16* b0 = BT + (size_t)(ng * 64 + cl) * NE + g * 8;
  bf16x8s av[2][4], bv[2][4];
#pragma unroll
  for (int i = 0; i < 4; i++) {
    av[0][i] = *(const bf16x8s*)(a0 + (size_t)(i * 16) * NE);
    bv[0][i] = *(const bf16x8s*)(b0 + (size_t)(i * 16) * NE);
  }
#pragma unroll
  for (int ks = 0; ks < 16; ks++) {
    const int cur = ks & 1;
    if (ks < 15) {
#pragma unroll
      for (int i = 0; i < 4; i++) {
        av[cur ^ 1][i] = *(const bf16x8s*)(a0 + (size_t)(i * 16) * NE + (ks + 1) * 32);
        bv[cur ^ 1][i] = *(const bf16x8s*)(b0 + (size_t)(i * 16) * NE + (ks + 1) * 32);
      }
    }
#pragma unroll
    for (int mi = 0; mi < 4; mi++)
#pragma unroll
      for (int ni = 0; ni < 4; ni++)
        acc[mi][ni] = mfma16(av[cur][mi], bv[cur][ni], acc[mi][ni]);
  }
#pragma unroll
  for (int mi = 0; mi < 4; mi++) {
#pragma unroll
    for (int ni = 0; ni < 4; ni++) {
      int colb = ng * 64 + ni * 16 + cl;
      if (colb < NV) {
        float bv2 = bias[colb];
#pragma unroll
        for (int j = 0; j < 4; j++) {
          int row = mg * 64 + mi * 16 + g * 4 + j;
          out[(size_t)row * NV + colb] = acc[mi][ni][j] + bv2;
        }
      }
    }
  }
}

extern "C" void kernel_launch(void* const* d_in, const int* in_sizes, int n_in,
                              void* d_out, int out_size, void* d_ws, size_t ws_size,
                              hipStream_t stream) {
  const int*   tokens = (const int*)d_in[0];
  const float* cnn    = (const float*)d_in[1];
  const float* emb    = (const float*)d_in[2];
  const float* w_in   = (const float*)d_in[3];
  const float* b_in   = (const float*)d_in[4];
  const float* w_r    = (const float*)d_in[5];
  const float* b_r    = (const float*)d_in[6];
  const float* w_u    = (const float*)d_in[7];
  const float* b_u    = (const float*)d_in[8];
  const float* w_h    = (const float*)d_in[9];
  const float* b_h    = (const float*)d_in[10];
  const float* w_out  = (const float*)d_in[11];
  const float* b_out  = (const float*)d_in[12];
  float* out = (float*)d_out;

  char* ws = (char*)d_ws;
  size_t off = 0;
  auto alloc = [&](size_t bytes) { char* p = ws + off; off += (bytes + 255) & ~(size_t)255; return p; };
  bf16*  x0      = (bf16*) alloc((size_t)2048 * 512 * 2);
  bf16*  seq0    = (bf16*) alloc((size_t)2048 * 512 * 2);
  bf16*  seq1    = (bf16*) alloc((size_t)2048 * 512 * 2);
  float* pre     = (float*)alloc((size_t)2 * PRE_SLOTS * 64 * 1536 * 4);
  float* h0f     = (float*)alloc((size_t)64 * 512 * 4);
  bf16*  h0b     = (bf16*) alloc((size_t)64 * 512 * 2);
  float* bias3   = (float*)alloc((size_t)2 * 1536 * 4);
  bf16*  cnn_b   = (bf16*) alloc((size_t)64 * 2048 * 2);
  bf16*  w_in_T  = (bf16*) alloc((size_t)512 * 2048 * 2);
  bf16*  w_ruh_T = (bf16*) alloc((size_t)2 * 1024 * 512 * 2);
  bf16*  w_hh_T  = (bf16*) alloc((size_t)2 * 512 * 512 * 2);
  bf16*  w_x_T   = (bf16*) alloc((size_t)2 * 1536 * 512 * 2);
  bf16*  w_out_T = (bf16*) alloc((size_t)10048 * 512 * 2);
  unsigned* flags = (unsigned*)alloc(1024);   // [2][4][32] u32
  (void)ws_size; (void)in_sizes; (void)n_in; (void)out_size;

  hipMemsetAsync(flags, 0, 1024, stream);
  hipMemsetAsync(w_out_T + (size_t)10000 * 512, 0, (size_t)48 * 512 * 2, stream);

  k_embed<<<2048, 256, 0, stream>>>(tokens, emb, x0);
  k_cvt<<<512, 256, 0, stream>>>(cnn, cnn_b, 64 * 2048);
  k_transpose<<<dim3(16, 64), 256, 0, stream>>>(w_in, w_in_T, NF, NH);
  k_transpose12<<<dim3(16, 16, 12), 256, 0, stream>>>(w_r, w_u, w_h, w_ruh_T, w_hh_T, w_x_T);
  k_transpose<<<dim3(313, 16), 256, 0, stream>>>(w_out, w_out_T, 512, NV);
  k_bias3all<<<12, 256, 0, stream>>>(b_r, b_u, b_h, bias3);

  k_gemm_h0<<<32, 256, 0, stream>>>(cnn_b, w_in_T, b_in, h0f, h0b);

  k_gru2<<<96, 512, 0, stream>>>(w_ruh_T, w_hh_T, w_x_T, bias3, h0f, h0b,
                                 x0, seq0, seq1, pre, flags);

  k_gemm_out<<<1256, 256, 0, stream>>>(seq1, w_out_T, b_out, out);
}